// Round 20
// baseline (56.001 us; speedup 1.0000x reference)
//
#include <hip/hip_runtime.h>
#include <math.h>

#define BATCH 16384
#define EDIM 128
#define RD (EDIM * EDIM)      // 16384 floats = 64 KB fp32 / 32 KB bf16
#define NREL 200
#define SPLIT 4
#define NBLK (NREL * SPLIT)   // 800
#define NTHR 512
#define QUARTER (BATCH / SPLIT)  // 4096
#define NJ (QUARTER / NTHR)      // 8
#define EBW 3
#define LISTCAP 128

// ws layout (32-bit words):
//  [0 .. NBLK)  csum[] (float, per-block partials; plain stores)
//  [2048]       arrival counter (memset to 0 each launch)

__device__ __forceinline__ int load_idx(const void* p, int b, int is64) {
    if (is64) return (int)((const long long*)p)[b];
    return ((const int*)p)[b];
}

// pack two fp32 -> (bf16(a) in lo16, bf16(b) in hi16), round-to-nearest-even
__device__ __forceinline__ unsigned int pack_bf16(float a, float b) {
    unsigned int ua = __float_as_uint(a);
    ua += 0x7fffu + ((ua >> 16) & 1u);
    unsigned int ub = __float_as_uint(b);
    ub += 0x7fffu + ((ub >> 16) & 1u);
    return (ua >> 16) | (ub & 0xffff0000u);
}

// Block (rid, quarter), 512 thr = 8 waves, 3 blocks/CU (LDS ~46 KB, VGPR<=85).
// R staged to LDS ONCE as packed bf16 (r2 from fp32 source); elements found by
// ballot scan; each wave serves ~3 elements with one LDS R-stream. Merged
// last-block final reduction (single dispatch + 4B memset).
__global__ __launch_bounds__(NTHR, 6) void rescal_kernel(
    const void* __restrict__ hI, const void* __restrict__ rI,
    const void* __restrict__ pI, const void* __restrict__ nI,
    const float* __restrict__ ent, const float* __restrict__ rel,
    float* __restrict__ ws, float* __restrict__ out) {
    const int t = threadIdx.x;
    const int bid0 = blockIdx.x;
    // rid-major XCD mapping: 4 quarters of a rid co-XCD
    const int xcd = bid0 & 7;
    const int slot = bid0 >> 3;
    const int rid = xcd + 8 * (slot >> 2);
    const int qtr = slot & 3;
    const int lane = t & 63;
    const int wave = t >> 6;    // 0..7
    const int c2 = lane * 2;

    __shared__ unsigned int Rlb[RD / 2];                            // 32 KB bf16x2
    __shared__ __attribute__((aligned(16))) float hL[8][EBW][EDIM]; // 12 KB
    __shared__ unsigned short list[LISTCAP];
    __shared__ unsigned int wtj[NJ][8];
    __shared__ unsigned int um8[8];
    __shared__ float rsq[8], wsum[8];
    __shared__ int s_last;

    // ---- dtype detect ----
    unsigned int o = 0u;
    if (t < 256) {
        o = ((const unsigned int*)hI)[2 * t + 1] | ((const unsigned int*)rI)[2 * t + 1] |
            ((const unsigned int*)pI)[2 * t + 1] | ((const unsigned int*)nI)[2 * t + 1];
    }
#pragma unroll
    for (int off = 32; off; off >>= 1) o |= __shfl_xor(o, off, 64);
    if (lane == 0) um8[wave] = o;
    __syncthreads();
    const int is64 = ((um8[0] | um8[1] | um8[2] | um8[3] |
                       um8[4] | um8[5] | um8[6] | um8[7]) == 0u) ? 1 : 0;

    // ---- stage R to LDS as bf16 pairs; r2 (fp32) inline ----
    const float* Rg = rel + (size_t)rid * RD;
    float r2p = 0.f;
#pragma unroll
    for (int it = 0; it < 8; ++it) {
        const int fidx = it * (NTHR * 4) + t * 4;
        const float4 v = *(const float4*)(Rg + fidx);
        r2p = fmaf(v.x, v.x, fmaf(v.y, v.y, fmaf(v.z, v.z, fmaf(v.w, v.w, r2p))));
        const int uidx = it * (NTHR * 2) + t * 2;
        Rlb[uidx] = pack_bf16(v.x, v.y);
        Rlb[uidx + 1] = pack_bf16(v.z, v.w);
    }
#pragma unroll
    for (int off = 32; off; off >>= 1) r2p += __shfl_xor(r2p, off, 64);
    if (lane == 0) rsq[wave] = r2p;

    // ---- coalesced ballot scan of my quarter ----
    const int qbase = qtr * QUARTER;
    unsigned long long bal[NJ];
#pragma unroll
    for (int j = 0; j < NJ; ++j) {
        const int rr = load_idx(rI, qbase + j * NTHR + t, is64);
        bal[j] = __ballot(rr == rid);
        if (lane == 0) wtj[j][wave] = (unsigned int)__popcll(bal[j]);
    }
    __syncthreads();   // Rlb, rsq, wtj ready

    int cnt;
    {
        unsigned int run = 0;
        const unsigned long long ltmask = (lane == 63) ? ~0ull >> 1
                                                       : (1ull << lane) - 1ull;
#pragma unroll
        for (int j = 0; j < NJ; ++j) {
            unsigned int wpre = 0, tj = 0;
#pragma unroll
            for (int w = 0; w < 8; ++w) {
                const unsigned int v = wtj[j][w];
                tj += v;
                wpre += (w < wave) ? v : 0;
            }
            if ((bal[j] >> lane) & 1ull) {
                const unsigned int rank =
                    run + wpre + (unsigned int)__popcll(bal[j] & ltmask);
                if (rank < LISTCAP) list[rank] = (unsigned short)(j * NTHR + t);
            }
            run += tj;
        }
        cnt = (int)run;
        if (cnt > LISTCAP) cnt = LISTCAP;
    }
    __syncthreads();   // list ready; no more block syncs until epilogue

    const float r2sum = rsq[0] + rsq[1] + rsq[2] + rsq[3] +
                        rsq[4] + rsq[5] + rsq[6] + rsq[7];

    // ---- per-wave independent range ----
    const int per_wave = (cnt + 7) >> 3;
    int lo = wave * per_wave;
    int hi = (wave + 1) * per_wave;
    if (lo > cnt) lo = cnt;
    if (hi > cnt) hi = cnt;

    float lsum = 0.f;  // lane-0-of-wave meaningful

    for (int e0 = lo; e0 < hi; e0 += EBW) {
        // uniform element handles; h-row fetched once, parked in LDS
        int bidx[EBW];
        float2 h2[EBW];
#pragma unroll
        for (int i = 0; i < EBW; ++i) {
            int e = e0 + i;
            if (e >= hi) e = hi - 1;
            int b = qbase + (int)list[e];
            b = __builtin_amdgcn_readfirstlane(b);
            bidx[i] = b;
            int hix = load_idx(hI, b, is64);
            hix = __builtin_amdgcn_readfirstlane(hix);
            h2[i] = *(const float2*)(ent + (size_t)hix * EDIM + c2);
            *(float2*)&hL[wave][i][c2] = h2[i];
        }

        // early tails (HBM misses drain under the d-loop)
        float2 tpv[EBW], tnv[EBW];
#pragma unroll
        for (int i = 0; i < EBW; ++i) {
            const int b = bidx[i];
            const int pi = __builtin_amdgcn_readfirstlane(load_idx(pI, b, is64));
            const int ni = __builtin_amdgcn_readfirstlane(load_idx(nI, b, is64));
            tpv[i] = *(const float2*)(ent + (size_t)pi * EDIM + c2);
            tnv[i] = *(const float2*)(ent + (size_t)ni * EDIM + c2);
        }

        // d-loop: R (ds_read_b32 bf16x2, 2-way = free) + h (broadcast b128)
        float2 acc[EBW];
#pragma unroll
        for (int i = 0; i < EBW; ++i) acc[i] = make_float2(0.f, 0.f);
#pragma unroll 4
        for (int db = 0; db < 32; ++db) {
            const float4 hv0 = *(const float4*)&hL[wave][0][db * 4];
            const float4 hv1 = *(const float4*)&hL[wave][1][db * 4];
            const float4 hv2 = *(const float4*)&hL[wave][2][db * 4];
#pragma unroll
            for (int jj = 0; jj < 4; ++jj) {
                const int d = db * 4 + jj;
                const unsigned int u = Rlb[d * 64 + lane];
                const float rx = __uint_as_float(u << 16);          // col c2
                const float ry = __uint_as_float(u & 0xffff0000u);  // col c2+1
                const float h0 = (jj == 0) ? hv0.x : (jj == 1) ? hv0.y : (jj == 2) ? hv0.z : hv0.w;
                const float h1 = (jj == 0) ? hv1.x : (jj == 1) ? hv1.y : (jj == 2) ? hv1.z : hv1.w;
                const float h2b = (jj == 0) ? hv2.x : (jj == 1) ? hv2.y : (jj == 2) ? hv2.z : hv2.w;
                acc[0].x = fmaf(rx, h0, acc[0].x);  acc[0].y = fmaf(ry, h0, acc[0].y);
                acc[1].x = fmaf(rx, h1, acc[1].x);  acc[1].y = fmaf(ry, h1, acc[1].y);
                acc[2].x = fmaf(rx, h2b, acc[2].x); acc[2].y = fmaf(ry, h2b, acc[2].y);
            }
        }

        // tails: all operands in registers
#pragma unroll
        for (int i = 0; i < EBW; ++i) {
            float dp = acc[i].x * tpv[i].x + acc[i].y * tpv[i].y;
            float dn = acc[i].x * tnv[i].x + acc[i].y * tnv[i].y;
            float e2 = h2[i].x * h2[i].x + h2[i].y * h2[i].y +
                       tpv[i].x * tpv[i].x + tpv[i].y * tpv[i].y +
                       tnv[i].x * tnv[i].x + tnv[i].y * tnv[i].y;
#pragma unroll
            for (int off = 32; off; off >>= 1) {
                dp += __shfl_xor(dp, off, 64);
                dn += __shfl_xor(dn, off, 64);
                e2 += __shfl_xor(e2, off, 64);
            }
            if (lane == 0 && (e0 + i) < hi) {
                const float x = dn - dp;  // neg_score - pos_score
                const float spl = (x > 0.f) ? (x + log1pf(expf(-x))) : log1pf(expf(x));
                lsum += spl + 1e-5f * 0.5f * (e2 + r2sum);
            }
        }
    }

    // ---- epilogue: block partial + last-block final reduction ----
    if (lane == 0) wsum[wave] = lsum;
    __syncthreads();
    if (t == 0) {
        ws[bid0] = wsum[0] + wsum[1] + wsum[2] + wsum[3] +
                   wsum[4] + wsum[5] + wsum[6] + wsum[7];
        __threadfence();
        unsigned int old = atomicAdd((unsigned int*)(ws + 2048), 1u);
        s_last = (old == (unsigned int)(NBLK - 1)) ? 1 : 0;
    }
    __syncthreads();
    if (s_last) {
        __threadfence();
        float a = 0.f;
        for (int i = t; i < NBLK; i += NTHR)
            a += __hip_atomic_load(&ws[i], __ATOMIC_ACQUIRE, __HIP_MEMORY_SCOPE_AGENT);
#pragma unroll
        for (int off = 32; off; off >>= 1) a += __shfl_down(a, off, 64);
        if (lane == 0) wsum[wave] = a;
        __syncthreads();
        if (t == 0)
            out[0] = (wsum[0] + wsum[1] + wsum[2] + wsum[3] +
                      wsum[4] + wsum[5] + wsum[6] + wsum[7]) * (1.0f / (float)BATCH);
    }
}

extern "C" void kernel_launch(void* const* d_in, const int* in_sizes, int n_in,
                              void* d_out, int out_size, void* d_ws, size_t ws_size,
                              hipStream_t stream) {
    const void* h = d_in[0];
    const void* r = d_in[1];
    const void* pt = d_in[2];
    const void* nt = d_in[3];
    const float* ent = (const float*)d_in[4];
    const float* rel = (const float*)d_in[5];

    // zero the arrival counter (ws word 2048) — capture-legal memset node
    hipMemsetAsync((void*)((char*)d_ws + 2048 * sizeof(float)), 0,
                   sizeof(unsigned int), stream);
    rescal_kernel<<<NBLK, NTHR, 0, stream>>>(h, r, pt, nt, ent, rel,
                                             (float*)d_ws, (float*)d_out);
}

// Round 21
// 47.127 us; speedup vs baseline: 1.1883x; 1.1883x over previous
//
#include <hip/hip_runtime.h>
#include <math.h>

#define BATCH 16384
#define EDIM 128
#define RD (EDIM * EDIM)      // 16384 floats = 64 KB
#define NREL 200
#define SPLIT 4
#define NBLK (NREL * SPLIT)   // 800
#define NTHR 512
#define QUARTER (BATCH / SPLIT)  // 4096
#define NJ (QUARTER / NTHR)      // 8
#define EBW 4
#define LISTCAP 256

// ws layout (floats): csum[0 .. NBLK) — per-block partials (plain stores)

__device__ __forceinline__ int load_idx(const void* p, int b, int is64) {
    if (is64) return (int)((const long long*)p)[b];
    return ((const int*)p)[b];
}

// Block (rid, quarter), 512 threads = 8 waves, 2 blocks/CU.
// R staged to LDS once (global R traffic = 51 MB total); each wave serves its
// ~3 elements with ONE conflict-free LDS R-stream; tails loaded exactly once.
__global__ __launch_bounds__(NTHR, 4) void rescal_kernel(
    const void* __restrict__ hI, const void* __restrict__ rI,
    const void* __restrict__ pI, const void* __restrict__ nI,
    const float* __restrict__ ent, const float* __restrict__ rel,
    float* __restrict__ csum) {
    const int t = threadIdx.x;
    const int bid0 = blockIdx.x;
    // rid-major XCD mapping: 4 quarters of a rid co-XCD -> staging L2-hits
    const int xcd = bid0 & 7;
    const int slot = bid0 >> 3;
    const int rid = xcd + 8 * (slot >> 2);
    const int qtr = slot & 3;
    const int lane = t & 63;
    const int wave = t >> 6;    // 0..7
    const int c2 = lane * 2;

    __shared__ __attribute__((aligned(16))) float Rl[RD];   // 64 KB
    __shared__ unsigned short list[LISTCAP];
    __shared__ unsigned int wtj[NJ][8];
    __shared__ unsigned int um8[8];
    __shared__ float rsq[8], wsum[8];

    // ---- dtype detect ----
    unsigned int o = 0u;
    if (t < 256) {
        o = ((const unsigned int*)hI)[2 * t + 1] | ((const unsigned int*)rI)[2 * t + 1] |
            ((const unsigned int*)pI)[2 * t + 1] | ((const unsigned int*)nI)[2 * t + 1];
    }
#pragma unroll
    for (int off = 32; off; off >>= 1) o |= __shfl_xor(o, off, 64);
    if (lane == 0) um8[wave] = o;
    __syncthreads();
    const int is64 = ((um8[0] | um8[1] | um8[2] | um8[3] |
                       um8[4] | um8[5] | um8[6] | um8[7]) == 0u) ? 1 : 0;

    // ---- stage R to LDS (coalesced float4) + r2 partial from staged values ----
    const float* Rg = rel + (size_t)rid * RD;
    float r2p = 0.f;
#pragma unroll
    for (int it = 0; it < 8; ++it) {
        const int idx = it * (NTHR * 4) + t * 4;
        const float4 v = *(const float4*)(Rg + idx);
        *(float4*)&Rl[idx] = v;
        r2p = fmaf(v.x, v.x, fmaf(v.y, v.y, fmaf(v.z, v.z, fmaf(v.w, v.w, r2p))));
    }
#pragma unroll
    for (int off = 32; off; off >>= 1) r2p += __shfl_xor(r2p, off, 64);
    if (lane == 0) rsq[wave] = r2p;

    // ---- coalesced ballot scan of my quarter ----
    const int qbase = qtr * QUARTER;
    unsigned long long bal[NJ];
#pragma unroll
    for (int j = 0; j < NJ; ++j) {
        const int rr = load_idx(rI, qbase + j * NTHR + t, is64);
        bal[j] = __ballot(rr == rid);
        if (lane == 0) wtj[j][wave] = (unsigned int)__popcll(bal[j]);
    }
    __syncthreads();   // Rl, rsq, wtj ready

    int cnt;
    {
        unsigned int run = 0;
        const unsigned long long ltmask = (lane == 63) ? ~0ull >> 1
                                                       : (1ull << lane) - 1ull;
#pragma unroll
        for (int j = 0; j < NJ; ++j) {
            unsigned int wpre = 0, tj = 0;
#pragma unroll
            for (int w = 0; w < 8; ++w) {
                const unsigned int v = wtj[j][w];
                tj += v;
                wpre += (w < wave) ? v : 0;
            }
            if ((bal[j] >> lane) & 1ull) {
                const unsigned int rank =
                    run + wpre + (unsigned int)__popcll(bal[j] & ltmask);
                if (rank < LISTCAP) list[rank] = (unsigned short)(j * NTHR + t);
            }
            run += tj;
        }
        cnt = (int)run;
        if (cnt > LISTCAP) cnt = LISTCAP;
    }
    __syncthreads();   // list ready; no more block syncs until epilogue

    const float r2sum = rsq[0] + rsq[1] + rsq[2] + rsq[3] +
                        rsq[4] + rsq[5] + rsq[6] + rsq[7];

    // ---- per-wave independent range (8 waves) ----
    const int per_wave = (cnt + 7) >> 3;
    int lo = wave * per_wave;
    int hi = (wave + 1) * per_wave;
    if (lo > cnt) lo = cnt;
    if (hi > cnt) hi = cnt;

    float lsum = 0.f;  // lane-0-of-wave meaningful

    for (int e0 = lo; e0 < hi; e0 += EBW) {
        // uniform element handles
        int bidx[EBW];
        const float* hrow[EBW];
#pragma unroll
        for (int i = 0; i < EBW; ++i) {
            int e = e0 + i;
            if (e >= hi) e = hi - 1;
            int b = qbase + (int)list[e];
            b = __builtin_amdgcn_readfirstlane(b);
            bidx[i] = b;
            int hix = load_idx(hI, b, is64);
            hix = __builtin_amdgcn_readfirstlane(hix);
            hrow[i] = ent + (size_t)hix * EDIM;
        }

        // d-loop: R from LDS (ds_read_b64, 2 lanes/bank = free), h uniform loads
        float2 acc[EBW];
#pragma unroll
        for (int i = 0; i < EBW; ++i) acc[i] = make_float2(0.f, 0.f);
#pragma unroll 4
        for (int db = 0; db < 32; ++db) {
            const float4 hv0 = *(const float4*)(hrow[0] + db * 4);
            const float4 hv1 = *(const float4*)(hrow[1] + db * 4);
            const float4 hv2 = *(const float4*)(hrow[2] + db * 4);
            const float4 hv3 = *(const float4*)(hrow[3] + db * 4);
#pragma unroll
            for (int jj = 0; jj < 4; ++jj) {
                const int d = db * 4 + jj;
                const float2 rv = *(const float2*)&Rl[d * EDIM + c2];
                const float h0 = (jj == 0) ? hv0.x : (jj == 1) ? hv0.y : (jj == 2) ? hv0.z : hv0.w;
                const float h1 = (jj == 0) ? hv1.x : (jj == 1) ? hv1.y : (jj == 2) ? hv1.z : hv1.w;
                const float h2 = (jj == 0) ? hv2.x : (jj == 1) ? hv2.y : (jj == 2) ? hv2.z : hv2.w;
                const float h3 = (jj == 0) ? hv3.x : (jj == 1) ? hv3.y : (jj == 2) ? hv3.z : hv3.w;
                acc[0].x = fmaf(rv.x, h0, acc[0].x); acc[0].y = fmaf(rv.y, h0, acc[0].y);
                acc[1].x = fmaf(rv.x, h1, acc[1].x); acc[1].y = fmaf(rv.y, h1, acc[1].y);
                acc[2].x = fmaf(rv.x, h2, acc[2].x); acc[2].y = fmaf(rv.y, h2, acc[2].y);
                acc[3].x = fmaf(rv.x, h3, acc[3].x); acc[3].y = fmaf(rv.y, h3, acc[3].y);
            }
        }

        // tails: exactly once per element
#pragma unroll
        for (int i = 0; i < EBW; ++i) {
            const int b = bidx[i];
            const int pi = __builtin_amdgcn_readfirstlane(load_idx(pI, b, is64));
            const int ni = __builtin_amdgcn_readfirstlane(load_idx(nI, b, is64));
            const float2 hv2 = *(const float2*)(hrow[i] + c2);
            const float2 tp2 = *(const float2*)(ent + (size_t)pi * EDIM + c2);
            const float2 tn2 = *(const float2*)(ent + (size_t)ni * EDIM + c2);
            float dp = acc[i].x * tp2.x + acc[i].y * tp2.y;
            float dn = acc[i].x * tn2.x + acc[i].y * tn2.y;
            float e2 = hv2.x * hv2.x + hv2.y * hv2.y + tp2.x * tp2.x + tp2.y * tp2.y +
                       tn2.x * tn2.x + tn2.y * tn2.y;
#pragma unroll
            for (int off = 32; off; off >>= 1) {
                dp += __shfl_xor(dp, off, 64);
                dn += __shfl_xor(dn, off, 64);
                e2 += __shfl_xor(e2, off, 64);
            }
            if (lane == 0 && (e0 + i) < hi) {
                const float x = dn - dp;  // neg_score - pos_score
                const float spl = (x > 0.f) ? (x + log1pf(expf(-x))) : log1pf(expf(x));
                lsum += spl + 1e-5f * 0.5f * (e2 + r2sum);
            }
        }
    }

    // ---- epilogue: plain store of block partial ----
    if (lane == 0) wsum[wave] = lsum;
    __syncthreads();
    if (t == 0) {
        csum[bid0] = wsum[0] + wsum[1] + wsum[2] + wsum[3] +
                     wsum[4] + wsum[5] + wsum[6] + wsum[7];
    }
}

__global__ __launch_bounds__(256) void reduce_kernel(const float* __restrict__ csum,
                                                     float* __restrict__ out) {
    const int t = threadIdx.x;
    float a = 0.f;
    for (int i = t; i < NBLK; i += 256) a += csum[i];
#pragma unroll
    for (int off = 32; off; off >>= 1) a += __shfl_down(a, off, 64);
    __shared__ float sm[4];
    if ((t & 63) == 0) sm[t >> 6] = a;
    __syncthreads();
    if (t == 0) out[0] = (sm[0] + sm[1] + sm[2] + sm[3]) * (1.0f / (float)BATCH);
}

extern "C" void kernel_launch(void* const* d_in, const int* in_sizes, int n_in,
                              void* d_out, int out_size, void* d_ws, size_t ws_size,
                              hipStream_t stream) {
    const void* h = d_in[0];
    const void* r = d_in[1];
    const void* pt = d_in[2];
    const void* nt = d_in[3];
    const float* ent = (const float*)d_in[4];
    const float* rel = (const float*)d_in[5];
    float* csum = (float*)d_ws;

    rescal_kernel<<<NBLK, NTHR, 0, stream>>>(h, r, pt, nt, ent, rel, csum);
    reduce_kernel<<<1, 256, 0, stream>>>(csum, (float*)d_out);
}